// Round 12
// baseline (239.297 us; speedup 1.0000x reference)
//
#include <hip/hip_runtime.h>
#include <math.h>

#define HID 32
#define TDIM 128
#define NNODE 100000
#define NEDGE 800000
#define NGRAPH 512
#define SCAN_BLK 1024
#define NBLK1 ((NNODE + SCAN_BLK - 1) / SCAN_BLK)   // 98
#define TPW 10   // edge tiles (of 16) per wave; 1250 blocks x 640 edges (fully resident)
#define NFRAG 18

typedef __attribute__((ext_vector_type(8))) short bf16x8;
typedef __attribute__((ext_vector_type(4))) float f32x4;

#define MFMA16(a, b, c) __builtin_amdgcn_mfma_f32_16x16x32_bf16(a, b, c, 0, 0, 0)

__device__ __forceinline__ float silu_f(float v) {
    return v * __builtin_amdgcn_rcpf(1.0f + __expf(-v));
}
__device__ __forceinline__ float sigmoid_f(float v) {
    return __builtin_amdgcn_rcpf(1.0f + __expf(-v));
}
__device__ __forceinline__ unsigned int bf16r(float f) {
    unsigned int u = __float_as_uint(f);
    return (u + 0x7FFFu + ((u >> 16) & 1u)) >> 16;   // RNE (cold paths)
}
__device__ __forceinline__ float bf16tof(unsigned int h) {
    return __uint_as_float(h << 16);
}
// pack two f32 -> two bf16 (round-half-up) in 3 VALU ops via v_perm_b32
__device__ __forceinline__ unsigned int pk2(float a, float b) {
    unsigned int ia = __float_as_uint(a) + 0x8000u;
    unsigned int ib = __float_as_uint(b) + 0x8000u;
    return __builtin_amdgcn_perm(ib, ia, 0x07060302u);
}
__device__ __forceinline__ bf16x8 pack8(f32x4 a, f32x4 b) {
    union { unsigned int u[4]; bf16x8 v; } r;
    r.u[0] = pk2(a[0], a[1]);
    r.u[1] = pk2(a[2], a[3]);
    r.u[2] = pk2(b[0], b[1]);
    r.u[3] = pk2(b[2], b[3]);
    return r.v;
}

// ---------------- K1: time MLP + zero degree counters ----------------
__global__ void time_mlp_kernel(const float* __restrict__ timein,
                                const float* __restrict__ w1, const float* __restrict__ b1,
                                const float* __restrict__ w2, const float* __restrict__ b2,
                                float* __restrict__ ss, int* __restrict__ cnt_int) {
    for (int i = blockIdx.x * 64 + threadIdx.x; i < NNODE; i += NGRAPH * 64) cnt_int[i] = 0;

    __shared__ float t[TDIM];
    __shared__ float h[2 * HID];
    const int g = blockIdx.x;
    const int c = threadIdx.x;  // 0..63
    t[c]      = timein[g * TDIM + c];
    t[64 + c] = timein[g * TDIM + 64 + c];
    __syncthreads();
    float acc = b1[c];
#pragma unroll
    for (int k = 0; k < TDIM; ++k) acc = fmaf(t[k], w1[k * 2 * HID + c], acc);
    h[c] = silu_f(acc);
    __syncthreads();
    float acc2 = b2[c];
#pragma unroll
    for (int k = 0; k < 2 * HID; ++k) acc2 = fmaf(h[k], w2[k * 2 * HID + c], acc2);
    ss[g * 2 * HID + c] = acc2;
}

// ---------------- K2: fused node-pre (float4) + histogram(+rank) + wf prep ----------------
__global__ void fused_pre_kernel(const float* __restrict__ x, const int* __restrict__ batch,
                                 const float* __restrict__ ss, const int* __restrict__ ei,
                                 unsigned short* __restrict__ x_bf, int* __restrict__ cnt_int,
                                 int* __restrict__ rank,
                                 const float* __restrict__ msg_w1, const float* __restrict__ msg_w2,
                                 const float* __restrict__ gate_w, const float* __restrict__ w_dist,
                                 const float* __restrict__ coord_w1, const float* __restrict__ comb_w1,
                                 const float* __restrict__ comb_w2,
                                 unsigned short* __restrict__ wf) {
    const int t = blockIdx.x * blockDim.x + threadIdx.x;  // 0..799999
    {
        const int base = t << 2;                 // element index (4 per thread)
        const int n = base >> 5, c = base & 31;
        const int g = batch[n];
        const float4 sc = *(const float4*)(ss + g * 64 + c);
        const float4 sh = *(const float4*)(ss + g * 64 + 32 + c);
        const float4 v  = *(const float4*)(x + base);
        ushort4 o;
        o.x = (unsigned short)bf16r(silu_f(fmaf(v.x, sc.x, v.x) + sh.x));
        o.y = (unsigned short)bf16r(silu_f(fmaf(v.y, sc.y, v.y) + sh.y));
        o.z = (unsigned short)bf16r(silu_f(fmaf(v.z, sc.z, v.z) + sh.z));
        o.w = (unsigned short)bf16r(silu_f(fmaf(v.w, sc.w, v.w) + sh.w));
        *(ushort4*)(x_bf + base) = o;
    }
    // histogram atomic ALSO yields this edge's rank within its destination segment
    if (t < NEDGE) rank[t] = atomicAdd(&cnt_int[ei[NEDGE + t]], 1);
    if (t < NFRAG * 512) {
        const int frag = t >> 9;
        const int idx = t & 511;
        const int lane = idx >> 3, j = idx & 7;
        const int n16 = lane & 15, k = (lane >> 4) * 8 + j;
        const float* W; int kt = 0, nt;
        if (frag < 4)       { W = msg_w1;   kt = frag >> 1;        nt = frag & 1; }
        else if (frag < 6)  { W = msg_w2;   nt = frag - 4; }
        else if (frag < 8)  { W = gate_w;   nt = frag - 6; }
        else if (frag < 10) { W = w_dist;   nt = frag - 8; }
        else if (frag < 12) { W = coord_w1; nt = frag - 10; }
        else if (frag < 16) { W = comb_w1;  kt = (frag - 12) >> 1; nt = (frag - 12) & 1; }
        else                { W = comb_w2;  nt = frag - 16; }
        wf[t] = (unsigned short)bf16r(W[(kt * 32 + k) * 32 + nt * 16 + n16]);
    }
}

// ---------------- K3: scan level 1 (R3-verified) ----------------
__global__ void scan1_kernel(const int* __restrict__ cnt_int, int* __restrict__ part,
                             int* __restrict__ blk) {
    __shared__ int s[SCAN_BLK];
    const int tid = threadIdx.x;
    const int i = blockIdx.x * SCAN_BLK + tid;
    const int v = (i < NNODE) ? cnt_int[i] : 0;
    s[tid] = v;
    __syncthreads();
    for (int off = 1; off < SCAN_BLK; off <<= 1) {
        int t = (tid >= off) ? s[tid - off] : 0;
        __syncthreads();
        s[tid] += t;
        __syncthreads();
    }
    part[i] = s[tid] - v;
    if (tid == SCAN_BLK - 1) blk[blockIdx.x] = s[tid];
}

// ---------------- K4: merged scan23 + scatter (R8-verified) ----------------
__global__ void scatter23_kernel(const int* __restrict__ part, const int* __restrict__ blk,
                                 const int* __restrict__ ei, const int* __restrict__ rank,
                                 int* __restrict__ offsets, int2* __restrict__ edge_sorted) {
    __shared__ int bp[128];
    const int tid = threadIdx.x;
    if (tid < 128) bp[tid] = (tid < NBLK1) ? blk[tid] : 0;
    __syncthreads();
    for (int off = 1; off < 128; off <<= 1) {
        int v = 0;
        if (tid < 128 && tid >= off) v = bp[tid - off];
        __syncthreads();
        if (tid < 128) bp[tid] += v;
        __syncthreads();
    }
    const int e = blockIdx.x * 256 + tid;
    const int vi = ei[e], vj = ei[NEDGE + e];
    const int boff = (vj >> 10) ? bp[(vj >> 10) - 1] : 0;
    edge_sorted[part[vj] + boff + rank[e]] = make_int2(vi, vj);
    if (e < NNODE) {
        const int b2 = (e >> 10) ? bp[(e >> 10) - 1] : 0;
        offsets[e] = part[e] + b2;
    }
}

// ---------------- K5: MFMA edge kernel (CSR-ordered; shadow-filled; cutoff folded into rbf) ----------------
// NOTE: no min-waves clause -- a VGPR cap of 64 spills the pipeline (R1, R5 evidence).
// R12 changes: (a) cutoff folded into the rbf A-operand before the dist_emb MFMA
// (cutoff*(rbf@W) == (cutoff*rbf)@W; cutoff is per-A-row and each lane holds its own
// edge's cutoff) -- removes 4 shuffles + 8 mults per lane/tile; (b) TPW 5->10 (1250
// blocks, fully resident) halves per-wave prologue overhead per tile.
__global__ __launch_bounds__(256) void edge_mfma_kernel(
    const int2* __restrict__ es, const unsigned short* __restrict__ x_bf,
    const float* __restrict__ pos,
    const float* __restrict__ rbf_means, const float* __restrict__ rbf_betas,
    const unsigned short* __restrict__ wf,
    const float* __restrict__ msg_b1, const float* __restrict__ msg_b2,
    const float* __restrict__ gate_b, const float* __restrict__ coord_b1,
    const float* __restrict__ coord_w2, const float* __restrict__ coord_b2,
    unsigned short* __restrict__ m_buf, float* __restrict__ pu_buf) {
    __shared__ float lmat[4][16 * 36];   // the only LDS: C->A layout bounce

    const int tid = threadIdx.x;
    const int wv = tid >> 6, lane = tid & 63;
    const int m16 = lane & 15, q = lane >> 4;
    float* Lm = lmat[wv];

    bf16x8 WF[12];
#pragma unroll
    for (int f = 0; f < 12; ++f) WF[f] = *(const bf16x8*)(wf + f * 512 + lane * 8);

    const float b1c0 = msg_b1[m16],   b1c1 = msg_b1[16 + m16];
    const float b2c0 = msg_b2[m16],   b2c1 = msg_b2[16 + m16];
    const float gbc0 = gate_b[m16],   gbc1 = gate_b[16 + m16];
    const float cb10 = coord_b1[m16], cb11 = coord_b1[16 + m16];
    const float cw20 = coord_w2[m16], cw21 = coord_w2[16 + m16];
    const float cb2  = coord_b2[0];
    const float4 rm0 = *(const float4*)(rbf_means + q * 8);
    const float4 rm1 = *(const float4*)(rbf_means + q * 8 + 4);
    // fold log2(e) into betas once: exp(-b*d^2) == 2^(-(b*log2e)*d^2)
    float4 rb0 = *(const float4*)(rbf_betas + q * 8);
    float4 rb1 = *(const float4*)(rbf_betas + q * 8 + 4);
    const float L2E = 1.4426950408889634f;
    rb0.x *= L2E; rb0.y *= L2E; rb0.z *= L2E; rb0.w *= L2E;
    rb1.x *= L2E; rb1.y *= L2E; rb1.z *= L2E; rb1.w *= L2E;

    const int wave_id = blockIdx.x * 4 + wv;
    const int e0 = wave_id * (TPW * 16) + m16;   // slot index of this lane's edge, tile 0
    const f32x4 z = {0.f, 0.f, 0.f, 0.f};

    // -------- pipeline prologue --------
    const int2 v0 = es[e0];
    bf16x8 xi_c = *(const bf16x8*)(x_bf + (size_t)v0.x * HID + q * 8);
    bf16x8 xj_c = *(const bf16x8*)(x_bf + (size_t)v0.y * HID + q * 8);
    float pi0_c = pos[v0.x * 3 + 0], pi1_c = pos[v0.x * 3 + 1], pi2_c = pos[v0.x * 3 + 2];
    float pj0_c = pos[v0.y * 3 + 0], pj1_c = pos[v0.y * 3 + 1], pj2_c = pos[v0.y * 3 + 2];
    int2 v_n = es[e0 + 16];

#pragma unroll 1
    for (int t = 0; t < TPW; ++t) {
        // ---- issue stage B for tile t+1 ----
        const bf16x8 xi_t = *(const bf16x8*)(x_bf + (size_t)v_n.x * HID + q * 8);
        const bf16x8 xj_t = *(const bf16x8*)(x_bf + (size_t)v_n.y * HID + q * 8);
        const float ti0 = pos[v_n.x * 3 + 0], ti1 = pos[v_n.x * 3 + 1], ti2 = pos[v_n.x * 3 + 2];
        const float tj0 = pos[v_n.y * 3 + 0], tj1 = pos[v_n.y * 3 + 1], tj2 = pos[v_n.y * 3 + 2];
        // ---- issue stage A for tile t+2 ----
        const int e2 = e0 + ((t + 2 < TPW) ? (t + 2) * 16 : 0);
        const int2 vA = es[e2];

        // ---- consume tile t ----
        const bf16x8 xi = xi_c, xj = xj_c;
        const int slot = e0 + t * 16;            // linear slot
        const float p0 = pi0_c - pj0_c;
        const float p1 = pi1_c - pj1_c;
        const float p2 = pi2_c - pj2_c;

        const float dist = sqrtf(p0 * p0 + p1 * p1 + p2 * p2);
        const float dcl = fminf(dist, 5.0f);
        const float cutoff = 0.5f * (__cosf(dcl * 0.6283185307179586f) + 1.0f);
        const float edm = __expf(-dist);

        // L1: h = silu(cat(xi,xj) @ msg_w1 + b1)
        f32x4 h0 = MFMA16(xi, WF[0], z); h0 = MFMA16(xj, WF[2], h0);
        f32x4 h1 = MFMA16(xi, WF[1], z); h1 = MFMA16(xj, WF[3], h1);
#pragma unroll
        for (int r = 0; r < 4; ++r) {
            Lm[(q * 4 + r) * 36 + m16]      = silu_f(h0[r] + b1c0);
            Lm[(q * 4 + r) * 36 + 16 + m16] = silu_f(h1[r] + b1c1);
        }

        // ======== bounce-1 wait shadow: everything independent of h ========
        // gate MFMA (xj only)
        f32x4 g0  = MFMA16(xj, WF[6], z), g1  = MFMA16(xj, WF[7], z);
        // rbf basis (edm only), scaled by cutoff (per-A-row fold), + dist_emb MFMA
        float rv[8];
        { float d;
          d = edm - rm0.x; rv[0] = __builtin_amdgcn_exp2f(-rb0.x * d * d);
          d = edm - rm0.y; rv[1] = __builtin_amdgcn_exp2f(-rb0.y * d * d);
          d = edm - rm0.z; rv[2] = __builtin_amdgcn_exp2f(-rb0.z * d * d);
          d = edm - rm0.w; rv[3] = __builtin_amdgcn_exp2f(-rb0.w * d * d);
          d = edm - rm1.x; rv[4] = __builtin_amdgcn_exp2f(-rb1.x * d * d);
          d = edm - rm1.y; rv[5] = __builtin_amdgcn_exp2f(-rb1.y * d * d);
          d = edm - rm1.z; rv[6] = __builtin_amdgcn_exp2f(-rb1.z * d * d);
          d = edm - rm1.w; rv[7] = __builtin_amdgcn_exp2f(-rb1.w * d * d); }
        bf16x8 rf;
        { union { unsigned int u[4]; bf16x8 v; } rr;
          rr.u[0] = pk2(cutoff * rv[0], cutoff * rv[1]);
          rr.u[1] = pk2(cutoff * rv[2], cutoff * rv[3]);
          rr.u[2] = pk2(cutoff * rv[4], cutoff * rv[5]);
          rr.u[3] = pk2(cutoff * rv[6], cutoff * rv[7]);
          rf = rr.v; }
        f32x4 d0 = MFMA16(rf, WF[8], z), d1 = MFMA16(rf, WF[9], z);
        // ===================================================================

        __builtin_amdgcn_s_waitcnt(0xC07F);  // lgkmcnt(0)
        f32x4 ha0 = *(const f32x4*)(Lm + m16 * 36 + q * 8);
        f32x4 ha1 = *(const f32x4*)(Lm + m16 * 36 + q * 8 + 4);
        const bf16x8 hf = pack8(ha0, ha1);

        // L2 MFMA (needs hf)
        f32x4 am0 = MFMA16(hf, WF[4], z), am1 = MFMA16(hf, WF[5], z);

        // combine in C-layout (cutoff already folded into d0/d1)
#pragma unroll
        for (int r = 0; r < 4; ++r) {
            const float mv0 = silu_f(am0[r] + b2c0) * sigmoid_f(g0[r] + gbc0) * d0[r];
            const float mv1 = silu_f(am1[r] + b2c1) * sigmoid_f(g1[r] + gbc1) * d1[r];
            Lm[(q * 4 + r) * 36 + m16]      = mv0;
            Lm[(q * 4 + r) * 36 + 16 + m16] = mv1;
        }

        // ======== bounce-2 wait shadow: pu geometry shuffles (p*, slot only) ========
        const int ep = q * 4 + (m16 & 3);
        const float sd0 = __shfl(p0, ep);
        const float sd1 = __shfl(p1, ep);
        const float sd2 = __shfl(p2, ep);
        // ===========================================================================

        __builtin_amdgcn_s_waitcnt(0xC07F);
        f32x4 ma0 = *(const f32x4*)(Lm + m16 * 36 + q * 8);
        f32x4 ma1 = *(const f32x4*)(Lm + m16 * 36 + q * 8 + 4);
        const bf16x8 mf = pack8(ma0, ma1);

        // coalesced streaming store (slot == linear edge index)
        *(bf16x8*)(m_buf + (size_t)slot * HID + q * 8) = mf;

        // coord layer + per-edge scalar s
        f32x4 c0 = MFMA16(mf, WF[10], z), c1 = MFMA16(mf, WF[11], z);
        float pp[4];
#pragma unroll
        for (int r = 0; r < 4; ++r)
            pp[r] = silu_f(c0[r] + cb10) * cw20 + silu_f(c1[r] + cb11) * cw21;
#pragma unroll
        for (int off = 1; off < 16; off <<= 1) {
#pragma unroll
            for (int r = 0; r < 4; ++r) pp[r] += __shfl_xor(pp[r], off);
        }

        const int tile_base = wave_id * (TPW * 16) + t * 16;
        const float sv = pp[m16 & 3] + cb2;
        if (m16 < 4) {
            ((float4*)pu_buf)[tile_base + ep] = make_float4(sd0 * sv, sd1 * sv, sd2 * sv, 0.0f);
        }

        // ---- rotate pipeline ----
        xi_c = xi_t; xj_c = xj_t;
        pi0_c = ti0; pi1_c = ti1; pi2_c = ti2;
        pj0_c = tj0; pj1_c = tj1; pj2_c = tj2;
        v_n = vA;
    }
}

// ---------------- K6: fused gather + node post (R7-verified) ----------------
__global__ __launch_bounds__(256) void node_post_mfma_kernel(
    const unsigned short* __restrict__ x_bf, const unsigned short* __restrict__ m_buf,
    const float* __restrict__ pu_buf,
    const int* __restrict__ offsets, const int* __restrict__ cnt_int,
    const float* __restrict__ pos, const unsigned short* __restrict__ wf,
    const float* __restrict__ comb_b1, const float* __restrict__ comb_b2,
    float* __restrict__ out_x, float* __restrict__ out_pos) {
    __shared__ float Lh[4][16 * 36];
    __shared__ float Lx[4][16 * 36];
    const int tid = threadIdx.x;
    const int wv = tid >> 6, lane = tid & 63;
    const int m16 = lane & 15, q = lane >> 4;
    const int wave_id = blockIdx.x * 4 + wv;
    if (wave_id * 16 >= NNODE) return;
    const int n = wave_id * 16 + m16;
    float* LH = Lh[wv];
    float* LX = Lx[wv];

    bf16x8 F[6];
#pragma unroll
    for (int f = 0; f < 6; ++f) F[f] = *(const bf16x8*)(wf + (12 + f) * 512 + lane * 8);
    const float b1c0 = comb_b1[m16], b1c1 = comb_b1[16 + m16];
    const float b2c0 = comb_b2[m16], b2c1 = comb_b2[16 + m16];

    const bf16x8 xa = *(const bf16x8*)(x_bf + (size_t)n * HID + q * 8);
    {
        f32x4 xd0, xd1;
#pragma unroll
        for (int jj = 0; jj < 4; ++jj) {
            xd0[jj] = bf16tof((unsigned short)xa[jj]);
            xd1[jj] = bf16tof((unsigned short)xa[4 + jj]);
        }
        *(f32x4*)(LX + m16 * 36 + q * 8) = xd0;
        *(f32x4*)(LX + m16 * 36 + q * 8 + 4) = xd1;
    }

    // gather m_i: 8-way unrolled (deg mean ~8 -> most loads in flight in one round)
    const int off = offsets[n];
    const int deg = cnt_int[n];
    float acc0[8] = {0.f, 0.f, 0.f, 0.f, 0.f, 0.f, 0.f, 0.f};
    float acc1[8] = {0.f, 0.f, 0.f, 0.f, 0.f, 0.f, 0.f, 0.f};
    int d = 0;
    for (; d + 8 <= deg; d += 8) {
        const bf16x8 m0 = *(const bf16x8*)(m_buf + (size_t)(off + d) * HID + q * 8);
        const bf16x8 m1 = *(const bf16x8*)(m_buf + (size_t)(off + d + 1) * HID + q * 8);
        const bf16x8 m2 = *(const bf16x8*)(m_buf + (size_t)(off + d + 2) * HID + q * 8);
        const bf16x8 m3 = *(const bf16x8*)(m_buf + (size_t)(off + d + 3) * HID + q * 8);
        const bf16x8 m4 = *(const bf16x8*)(m_buf + (size_t)(off + d + 4) * HID + q * 8);
        const bf16x8 m5 = *(const bf16x8*)(m_buf + (size_t)(off + d + 5) * HID + q * 8);
        const bf16x8 m6 = *(const bf16x8*)(m_buf + (size_t)(off + d + 6) * HID + q * 8);
        const bf16x8 m7 = *(const bf16x8*)(m_buf + (size_t)(off + d + 7) * HID + q * 8);
#pragma unroll
        for (int jj = 0; jj < 8; ++jj) {
            acc0[jj] += (bf16tof((unsigned short)m0[jj]) + bf16tof((unsigned short)m2[jj]))
                      + (bf16tof((unsigned short)m4[jj]) + bf16tof((unsigned short)m6[jj]));
            acc1[jj] += (bf16tof((unsigned short)m1[jj]) + bf16tof((unsigned short)m3[jj]))
                      + (bf16tof((unsigned short)m5[jj]) + bf16tof((unsigned short)m7[jj]));
        }
    }
    for (; d + 2 <= deg; d += 2) {
        const bf16x8 m0 = *(const bf16x8*)(m_buf + (size_t)(off + d) * HID + q * 8);
        const bf16x8 m1 = *(const bf16x8*)(m_buf + (size_t)(off + d + 1) * HID + q * 8);
#pragma unroll
        for (int jj = 0; jj < 8; ++jj) {
            acc0[jj] += bf16tof((unsigned short)m0[jj]);
            acc1[jj] += bf16tof((unsigned short)m1[jj]);
        }
    }
    if (d < deg) {
        const bf16x8 m0 = *(const bf16x8*)(m_buf + (size_t)(off + d) * HID + q * 8);
#pragma unroll
        for (int jj = 0; jj < 8; ++jj) acc0[jj] += bf16tof((unsigned short)m0[jj]);
    }
    bf16x8 mi;
    { union { unsigned int u[4]; bf16x8 v; } rr;
      rr.u[0] = pk2(acc0[0] + acc1[0], acc0[1] + acc1[1]);
      rr.u[1] = pk2(acc0[2] + acc1[2], acc0[3] + acc1[3]);
      rr.u[2] = pk2(acc0[4] + acc1[4], acc0[5] + acc1[5]);
      rr.u[3] = pk2(acc0[6] + acc1[6], acc0[7] + acc1[7]);
      mi = rr.v; }

    float a0 = 0.f, a1 = 0.f, a2 = 0.f;
    for (int dd = q; dd < deg; dd += 4) {
        const float4 p = ((const float4*)pu_buf)[off + dd];
        a0 += p.x; a1 += p.y; a2 += p.z;
    }
    a0 += __shfl_xor(a0, 16); a0 += __shfl_xor(a0, 32);
    a1 += __shfl_xor(a1, 16); a1 += __shfl_xor(a1, 32);
    a2 += __shfl_xor(a2, 16); a2 += __shfl_xor(a2, 32);

    const f32x4 z = {0.f, 0.f, 0.f, 0.f};
    f32x4 h0 = MFMA16(xa, F[0], z); h0 = MFMA16(mi, F[2], h0);
    f32x4 h1 = MFMA16(xa, F[1], z); h1 = MFMA16(mi, F[3], h1);
#pragma unroll
    for (int r = 0; r < 4; ++r) {
        LH[(q * 4 + r) * 36 + m16]      = silu_f(h0[r] + b1c0);
        LH[(q * 4 + r) * 36 + 16 + m16] = silu_f(h1[r] + b1c1);
    }
    __builtin_amdgcn_s_waitcnt(0xC07F);
    f32x4 ha0 = *(const f32x4*)(LH + m16 * 36 + q * 8);
    f32x4 ha1 = *(const f32x4*)(LH + m16 * 36 + q * 8 + 4);
    const bf16x8 hf = pack8(ha0, ha1);

    f32x4 c0 = MFMA16(hf, F[4], z), c1 = MFMA16(hf, F[5], z);
#pragma unroll
    for (int r = 0; r < 4; ++r) {
        const float xv0 = LX[(q * 4 + r) * 36 + m16];
        const float xv1 = LX[(q * 4 + r) * 36 + 16 + m16];
        LH[(q * 4 + r) * 36 + m16]      = silu_f(xv0 + c0[r] + b2c0);
        LH[(q * 4 + r) * 36 + 16 + m16] = silu_f(xv1 + c1[r] + b2c1);
    }
    __builtin_amdgcn_s_waitcnt(0xC07F);
    {
        const int row = lane >> 2, col = (lane & 3) * 8;
        f32x4 o0 = *(const f32x4*)(LH + row * 36 + col);
        f32x4 o1 = *(const f32x4*)(LH + row * 36 + col + 4);
        float* dst = out_x + (size_t)(wave_id * 16 + row) * HID + col;
        *(f32x4*)dst = o0;
        *(f32x4*)(dst + 4) = o1;
    }
    if (q == 0) {
        const float inv = __builtin_amdgcn_rcpf(fmaxf((float)deg, 1.0f));
        out_pos[n * 3 + 0] = fmaf(a0, inv, pos[n * 3 + 0]);
        out_pos[n * 3 + 1] = fmaf(a1, inv, pos[n * 3 + 1]);
        out_pos[n * 3 + 2] = fmaf(a2, inv, pos[n * 3 + 2]);
    }
}

// ---------------- launch ----------------
extern "C" void kernel_launch(void* const* d_in, const int* in_sizes, int n_in,
                              void* d_out, int out_size, void* d_ws, size_t ws_size,
                              hipStream_t stream) {
    const float* x        = (const float*)d_in[0];
    const int*   ei       = (const int*)d_in[1];
    const float* pos      = (const float*)d_in[2];
    const float* timein   = (const float*)d_in[3];
    const int*   batch    = (const int*)d_in[4];
    const float* rbfm     = (const float*)d_in[5];
    const float* rbfb     = (const float*)d_in[6];
    const float* w_dist   = (const float*)d_in[7];
    const float* msg_w1   = (const float*)d_in[8];
    const float* msg_b1   = (const float*)d_in[9];
    const float* msg_w2   = (const float*)d_in[10];
    const float* msg_b2   = (const float*)d_in[11];
    const float* gate_w   = (const float*)d_in[12];
    const float* gate_b   = (const float*)d_in[13];
    const float* time_w1  = (const float*)d_in[14];
    const float* time_b1  = (const float*)d_in[15];
    const float* time_w2  = (const float*)d_in[16];
    const float* time_b2  = (const float*)d_in[17];
    const float* comb_w1  = (const float*)d_in[18];
    const float* comb_b1  = (const float*)d_in[19];
    const float* comb_w2  = (const float*)d_in[20];
    const float* comb_b2  = (const float*)d_in[21];
    const float* coord_w1 = (const float*)d_in[22];
    const float* coord_b1 = (const float*)d_in[23];
    const float* coord_w2 = (const float*)d_in[24];
    const float* coord_b2 = (const float*)d_in[25];

    char* w = (char*)d_ws;
    float* ss      = (float*)w;  w += (size_t)NGRAPH * 64 * 4;
    int*   cnt     = (int*)w;    w += (size_t)NNODE * 4;
    int*   offsets = (int*)w;    w += (size_t)NNODE * 4;
    int*   part    = (int*)w;    w += (size_t)NBLK1 * SCAN_BLK * 4;
    int*   blk     = (int*)w;    w += 128 * 4;
    int*   rank    = (int*)w;    w += (size_t)NEDGE * 4;
    w = (char*)(((size_t)w + 15) & ~(size_t)15);
    int2*  es      = (int2*)w;   w += (size_t)NEDGE * 8;
    unsigned short* x_bf = (unsigned short*)w;  w += (size_t)NNODE * HID * 2;
    unsigned short* wf   = (unsigned short*)w;  w += (size_t)NFRAG * 512 * 2;
    w = (char*)(((size_t)w + 15) & ~(size_t)15);
    unsigned short* m_buf = (unsigned short*)w; w += (size_t)NEDGE * HID * 2;
    float* pu_buf  = (float*)w;

    float* out_x   = (float*)d_out;
    float* out_pos = out_x + NNODE * HID;

    time_mlp_kernel<<<NGRAPH, 64, 0, stream>>>(timein, time_w1, time_b1, time_w2, time_b2,
                                               ss, cnt);
    fused_pre_kernel<<<NEDGE / 256, 256, 0, stream>>>(x, batch, ss, ei, x_bf, cnt,
                                                      rank,
                                                      msg_w1, msg_w2, gate_w, w_dist,
                                                      coord_w1, comb_w1, comb_w2, wf);
    scan1_kernel<<<NBLK1, SCAN_BLK, 0, stream>>>(cnt, part, blk);
    scatter23_kernel<<<NEDGE / 256, 256, 0, stream>>>(part, blk, ei, rank, offsets, es);
    edge_mfma_kernel<<<NEDGE / (TPW * 64), 256, 0, stream>>>(es, x_bf, pos, rbfm, rbfb, wf,
                                                             msg_b1, msg_b2, gate_b, coord_b1,
                                                             coord_w2, coord_b2,
                                                             m_buf, pu_buf);
    node_post_mfma_kernel<<<(NNODE / 16 + 3) / 4, 256, 0, stream>>>(x_bf, m_buf, pu_buf,
                                                                    offsets, cnt, pos, wf,
                                                                    comb_b1, comb_b2,
                                                                    out_x, out_pos);
}

// Round 13
// 234.002 us; speedup vs baseline: 1.0226x; 1.0226x over previous
//
#include <hip/hip_runtime.h>
#include <math.h>

#define HID 32
#define TDIM 128
#define NNODE 100000
#define NEDGE 800000
#define NGRAPH 512
#define SCAN_BLK 1024
#define NBLK1 ((NNODE + SCAN_BLK - 1) / SCAN_BLK)   // 98
#define TPW 5   // edge tiles (of 16) per wave; 2500 blocks (R12's TPW=10 hurt tail occupancy)
#define NFRAG 18

typedef __attribute__((ext_vector_type(8))) short bf16x8;
typedef __attribute__((ext_vector_type(4))) float f32x4;

#define MFMA16(a, b, c) __builtin_amdgcn_mfma_f32_16x16x32_bf16(a, b, c, 0, 0, 0)

__device__ __forceinline__ float silu_f(float v) {
    return v * __builtin_amdgcn_rcpf(1.0f + __expf(-v));
}
__device__ __forceinline__ float sigmoid_f(float v) {
    return __builtin_amdgcn_rcpf(1.0f + __expf(-v));
}
__device__ __forceinline__ unsigned int bf16r(float f) {
    unsigned int u = __float_as_uint(f);
    return (u + 0x7FFFu + ((u >> 16) & 1u)) >> 16;   // RNE (cold paths)
}
__device__ __forceinline__ float bf16tof(unsigned int h) {
    return __uint_as_float(h << 16);
}
// pack two f32 -> two bf16 (round-half-up) in 3 VALU ops via v_perm_b32
__device__ __forceinline__ unsigned int pk2(float a, float b) {
    unsigned int ia = __float_as_uint(a) + 0x8000u;
    unsigned int ib = __float_as_uint(b) + 0x8000u;
    return __builtin_amdgcn_perm(ib, ia, 0x07060302u);
}
__device__ __forceinline__ bf16x8 pack8(f32x4 a, f32x4 b) {
    union { unsigned int u[4]; bf16x8 v; } r;
    r.u[0] = pk2(a[0], a[1]);
    r.u[1] = pk2(a[2], a[3]);
    r.u[2] = pk2(b[0], b[1]);
    r.u[3] = pk2(b[2], b[3]);
    return r.v;
}

// ---------------- K1: time MLP + zero degree counters ----------------
__global__ void time_mlp_kernel(const float* __restrict__ timein,
                                const float* __restrict__ w1, const float* __restrict__ b1,
                                const float* __restrict__ w2, const float* __restrict__ b2,
                                float* __restrict__ ss, int* __restrict__ cnt_int) {
    for (int i = blockIdx.x * 64 + threadIdx.x; i < NNODE; i += NGRAPH * 64) cnt_int[i] = 0;

    __shared__ float t[TDIM];
    __shared__ float h[2 * HID];
    const int g = blockIdx.x;
    const int c = threadIdx.x;  // 0..63
    t[c]      = timein[g * TDIM + c];
    t[64 + c] = timein[g * TDIM + 64 + c];
    __syncthreads();
    float acc = b1[c];
#pragma unroll
    for (int k = 0; k < TDIM; ++k) acc = fmaf(t[k], w1[k * 2 * HID + c], acc);
    h[c] = silu_f(acc);
    __syncthreads();
    float acc2 = b2[c];
#pragma unroll
    for (int k = 0; k < 2 * HID; ++k) acc2 = fmaf(h[k], w2[k * 2 * HID + c], acc2);
    ss[g * 2 * HID + c] = acc2;
}

// ---------------- K2: fused node-pre (float4) + histogram(+rank) + wf prep ----------------
__global__ void fused_pre_kernel(const float* __restrict__ x, const int* __restrict__ batch,
                                 const float* __restrict__ ss, const int* __restrict__ ei,
                                 unsigned short* __restrict__ x_bf, int* __restrict__ cnt_int,
                                 int* __restrict__ rank,
                                 const float* __restrict__ msg_w1, const float* __restrict__ msg_w2,
                                 const float* __restrict__ gate_w, const float* __restrict__ w_dist,
                                 const float* __restrict__ coord_w1, const float* __restrict__ comb_w1,
                                 const float* __restrict__ comb_w2,
                                 unsigned short* __restrict__ wf) {
    const int t = blockIdx.x * blockDim.x + threadIdx.x;  // 0..799999
    {
        const int base = t << 2;                 // element index (4 per thread)
        const int n = base >> 5, c = base & 31;
        const int g = batch[n];
        const float4 sc = *(const float4*)(ss + g * 64 + c);
        const float4 sh = *(const float4*)(ss + g * 64 + 32 + c);
        const float4 v  = *(const float4*)(x + base);
        ushort4 o;
        o.x = (unsigned short)bf16r(silu_f(fmaf(v.x, sc.x, v.x) + sh.x));
        o.y = (unsigned short)bf16r(silu_f(fmaf(v.y, sc.y, v.y) + sh.y));
        o.z = (unsigned short)bf16r(silu_f(fmaf(v.z, sc.z, v.z) + sh.z));
        o.w = (unsigned short)bf16r(silu_f(fmaf(v.w, sc.w, v.w) + sh.w));
        *(ushort4*)(x_bf + base) = o;
    }
    // histogram atomic ALSO yields this edge's rank within its destination segment
    if (t < NEDGE) rank[t] = atomicAdd(&cnt_int[ei[NEDGE + t]], 1);
    if (t < NFRAG * 512) {
        const int frag = t >> 9;
        const int idx = t & 511;
        const int lane = idx >> 3, j = idx & 7;
        const int n16 = lane & 15, k = (lane >> 4) * 8 + j;
        const float* W; int kt = 0, nt;
        if (frag < 4)       { W = msg_w1;   kt = frag >> 1;        nt = frag & 1; }
        else if (frag < 6)  { W = msg_w2;   nt = frag - 4; }
        else if (frag < 8)  { W = gate_w;   nt = frag - 6; }
        else if (frag < 10) { W = w_dist;   nt = frag - 8; }
        else if (frag < 12) { W = coord_w1; nt = frag - 10; }
        else if (frag < 16) { W = comb_w1;  kt = (frag - 12) >> 1; nt = (frag - 12) & 1; }
        else                { W = comb_w2;  nt = frag - 16; }
        wf[t] = (unsigned short)bf16r(W[(kt * 32 + k) * 32 + nt * 16 + n16]);
    }
}

// ---------------- K3: scan level 1 (R3-verified) ----------------
__global__ void scan1_kernel(const int* __restrict__ cnt_int, int* __restrict__ part,
                             int* __restrict__ blk) {
    __shared__ int s[SCAN_BLK];
    const int tid = threadIdx.x;
    const int i = blockIdx.x * SCAN_BLK + tid;
    const int v = (i < NNODE) ? cnt_int[i] : 0;
    s[tid] = v;
    __syncthreads();
    for (int off = 1; off < SCAN_BLK; off <<= 1) {
        int t = (tid >= off) ? s[tid - off] : 0;
        __syncthreads();
        s[tid] += t;
        __syncthreads();
    }
    part[i] = s[tid] - v;
    if (tid == SCAN_BLK - 1) blk[blockIdx.x] = s[tid];
}

// ---------------- K4: merged scan23 + scatter (R8-verified) ----------------
__global__ void scatter23_kernel(const int* __restrict__ part, const int* __restrict__ blk,
                                 const int* __restrict__ ei, const int* __restrict__ rank,
                                 int* __restrict__ offsets, int2* __restrict__ edge_sorted) {
    __shared__ int bp[128];
    const int tid = threadIdx.x;
    if (tid < 128) bp[tid] = (tid < NBLK1) ? blk[tid] : 0;
    __syncthreads();
    for (int off = 1; off < 128; off <<= 1) {
        int v = 0;
        if (tid < 128 && tid >= off) v = bp[tid - off];
        __syncthreads();
        if (tid < 128) bp[tid] += v;
        __syncthreads();
    }
    const int e = blockIdx.x * 256 + tid;
    const int vi = ei[e], vj = ei[NEDGE + e];
    const int boff = (vj >> 10) ? bp[(vj >> 10) - 1] : 0;
    edge_sorted[part[vj] + boff + rank[e]] = make_int2(vi, vj);
    if (e < NNODE) {
        const int b2 = (e >> 10) ? bp[(e >> 10) - 1] : 0;
        offsets[e] = part[e] + b2;
    }
}

// ---------------- K5: MFMA edge kernel (CSR-ordered; shadow-filled; cutoff folded; TPW=5) ----------------
// NOTE: no min-waves clause -- a VGPR cap of 64 spills the pipeline (R1, R5 evidence).
// R13: best-known config = R11 structure (TPW=5, shadow-filled bounces) + R12's
// cutoff-into-rbf fold (strictly fewer ops, correctness-verified in R12).
// TPW=10 reverted: -2.7pp occupancy from tail quantization, no edge gain.
__global__ __launch_bounds__(256) void edge_mfma_kernel(
    const int2* __restrict__ es, const unsigned short* __restrict__ x_bf,
    const float* __restrict__ pos,
    const float* __restrict__ rbf_means, const float* __restrict__ rbf_betas,
    const unsigned short* __restrict__ wf,
    const float* __restrict__ msg_b1, const float* __restrict__ msg_b2,
    const float* __restrict__ gate_b, const float* __restrict__ coord_b1,
    const float* __restrict__ coord_w2, const float* __restrict__ coord_b2,
    unsigned short* __restrict__ m_buf, float* __restrict__ pu_buf) {
    __shared__ float lmat[4][16 * 36];   // the only LDS: C->A layout bounce

    const int tid = threadIdx.x;
    const int wv = tid >> 6, lane = tid & 63;
    const int m16 = lane & 15, q = lane >> 4;
    float* Lm = lmat[wv];

    bf16x8 WF[12];
#pragma unroll
    for (int f = 0; f < 12; ++f) WF[f] = *(const bf16x8*)(wf + f * 512 + lane * 8);

    const float b1c0 = msg_b1[m16],   b1c1 = msg_b1[16 + m16];
    const float b2c0 = msg_b2[m16],   b2c1 = msg_b2[16 + m16];
    const float gbc0 = gate_b[m16],   gbc1 = gate_b[16 + m16];
    const float cb10 = coord_b1[m16], cb11 = coord_b1[16 + m16];
    const float cw20 = coord_w2[m16], cw21 = coord_w2[16 + m16];
    const float cb2  = coord_b2[0];
    const float4 rm0 = *(const float4*)(rbf_means + q * 8);
    const float4 rm1 = *(const float4*)(rbf_means + q * 8 + 4);
    // fold log2(e) into betas once: exp(-b*d^2) == 2^(-(b*log2e)*d^2)
    float4 rb0 = *(const float4*)(rbf_betas + q * 8);
    float4 rb1 = *(const float4*)(rbf_betas + q * 8 + 4);
    const float L2E = 1.4426950408889634f;
    rb0.x *= L2E; rb0.y *= L2E; rb0.z *= L2E; rb0.w *= L2E;
    rb1.x *= L2E; rb1.y *= L2E; rb1.z *= L2E; rb1.w *= L2E;

    const int wave_id = blockIdx.x * 4 + wv;
    const int e0 = wave_id * (TPW * 16) + m16;   // slot index of this lane's edge, tile 0
    const f32x4 z = {0.f, 0.f, 0.f, 0.f};

    // -------- pipeline prologue --------
    const int2 v0 = es[e0];
    bf16x8 xi_c = *(const bf16x8*)(x_bf + (size_t)v0.x * HID + q * 8);
    bf16x8 xj_c = *(const bf16x8*)(x_bf + (size_t)v0.y * HID + q * 8);
    float pi0_c = pos[v0.x * 3 + 0], pi1_c = pos[v0.x * 3 + 1], pi2_c = pos[v0.x * 3 + 2];
    float pj0_c = pos[v0.y * 3 + 0], pj1_c = pos[v0.y * 3 + 1], pj2_c = pos[v0.y * 3 + 2];
    int2 v_n = es[e0 + 16];

#pragma unroll 1
    for (int t = 0; t < TPW; ++t) {
        // ---- issue stage B for tile t+1 ----
        const bf16x8 xi_t = *(const bf16x8*)(x_bf + (size_t)v_n.x * HID + q * 8);
        const bf16x8 xj_t = *(const bf16x8*)(x_bf + (size_t)v_n.y * HID + q * 8);
        const float ti0 = pos[v_n.x * 3 + 0], ti1 = pos[v_n.x * 3 + 1], ti2 = pos[v_n.x * 3 + 2];
        const float tj0 = pos[v_n.y * 3 + 0], tj1 = pos[v_n.y * 3 + 1], tj2 = pos[v_n.y * 3 + 2];
        // ---- issue stage A for tile t+2 ----
        const int e2 = e0 + ((t + 2 < TPW) ? (t + 2) * 16 : 0);
        const int2 vA = es[e2];

        // ---- consume tile t ----
        const bf16x8 xi = xi_c, xj = xj_c;
        const int slot = e0 + t * 16;            // linear slot
        const float p0 = pi0_c - pj0_c;
        const float p1 = pi1_c - pj1_c;
        const float p2 = pi2_c - pj2_c;

        const float dist = sqrtf(p0 * p0 + p1 * p1 + p2 * p2);
        const float dcl = fminf(dist, 5.0f);
        const float cutoff = 0.5f * (__cosf(dcl * 0.6283185307179586f) + 1.0f);
        const float edm = __expf(-dist);

        // L1: h = silu(cat(xi,xj) @ msg_w1 + b1)
        f32x4 h0 = MFMA16(xi, WF[0], z); h0 = MFMA16(xj, WF[2], h0);
        f32x4 h1 = MFMA16(xi, WF[1], z); h1 = MFMA16(xj, WF[3], h1);
#pragma unroll
        for (int r = 0; r < 4; ++r) {
            Lm[(q * 4 + r) * 36 + m16]      = silu_f(h0[r] + b1c0);
            Lm[(q * 4 + r) * 36 + 16 + m16] = silu_f(h1[r] + b1c1);
        }

        // ======== bounce-1 wait shadow: everything independent of h ========
        // gate MFMA (xj only)
        f32x4 g0  = MFMA16(xj, WF[6], z), g1  = MFMA16(xj, WF[7], z);
        // rbf basis (edm only), scaled by cutoff (per-A-row fold), + dist_emb MFMA
        float rv[8];
        { float d;
          d = edm - rm0.x; rv[0] = __builtin_amdgcn_exp2f(-rb0.x * d * d);
          d = edm - rm0.y; rv[1] = __builtin_amdgcn_exp2f(-rb0.y * d * d);
          d = edm - rm0.z; rv[2] = __builtin_amdgcn_exp2f(-rb0.z * d * d);
          d = edm - rm0.w; rv[3] = __builtin_amdgcn_exp2f(-rb0.w * d * d);
          d = edm - rm1.x; rv[4] = __builtin_amdgcn_exp2f(-rb1.x * d * d);
          d = edm - rm1.y; rv[5] = __builtin_amdgcn_exp2f(-rb1.y * d * d);
          d = edm - rm1.z; rv[6] = __builtin_amdgcn_exp2f(-rb1.z * d * d);
          d = edm - rm1.w; rv[7] = __builtin_amdgcn_exp2f(-rb1.w * d * d); }
        bf16x8 rf;
        { union { unsigned int u[4]; bf16x8 v; } rr;
          rr.u[0] = pk2(cutoff * rv[0], cutoff * rv[1]);
          rr.u[1] = pk2(cutoff * rv[2], cutoff * rv[3]);
          rr.u[2] = pk2(cutoff * rv[4], cutoff * rv[5]);
          rr.u[3] = pk2(cutoff * rv[6], cutoff * rv[7]);
          rf = rr.v; }
        f32x4 d0 = MFMA16(rf, WF[8], z), d1 = MFMA16(rf, WF[9], z);
        // ===================================================================

        __builtin_amdgcn_s_waitcnt(0xC07F);  // lgkmcnt(0)
        f32x4 ha0 = *(const f32x4*)(Lm + m16 * 36 + q * 8);
        f32x4 ha1 = *(const f32x4*)(Lm + m16 * 36 + q * 8 + 4);
        const bf16x8 hf = pack8(ha0, ha1);

        // L2 MFMA (needs hf)
        f32x4 am0 = MFMA16(hf, WF[4], z), am1 = MFMA16(hf, WF[5], z);

        // combine in C-layout (cutoff already folded into d0/d1)
#pragma unroll
        for (int r = 0; r < 4; ++r) {
            const float mv0 = silu_f(am0[r] + b2c0) * sigmoid_f(g0[r] + gbc0) * d0[r];
            const float mv1 = silu_f(am1[r] + b2c1) * sigmoid_f(g1[r] + gbc1) * d1[r];
            Lm[(q * 4 + r) * 36 + m16]      = mv0;
            Lm[(q * 4 + r) * 36 + 16 + m16] = mv1;
        }

        // ======== bounce-2 wait shadow: pu geometry shuffles (p*, slot only) ========
        const int ep = q * 4 + (m16 & 3);
        const float sd0 = __shfl(p0, ep);
        const float sd1 = __shfl(p1, ep);
        const float sd2 = __shfl(p2, ep);
        // ===========================================================================

        __builtin_amdgcn_s_waitcnt(0xC07F);
        f32x4 ma0 = *(const f32x4*)(Lm + m16 * 36 + q * 8);
        f32x4 ma1 = *(const f32x4*)(Lm + m16 * 36 + q * 8 + 4);
        const bf16x8 mf = pack8(ma0, ma1);

        // coalesced streaming store (slot == linear edge index)
        *(bf16x8*)(m_buf + (size_t)slot * HID + q * 8) = mf;

        // coord layer + per-edge scalar s
        f32x4 c0 = MFMA16(mf, WF[10], z), c1 = MFMA16(mf, WF[11], z);
        float pp[4];
#pragma unroll
        for (int r = 0; r < 4; ++r)
            pp[r] = silu_f(c0[r] + cb10) * cw20 + silu_f(c1[r] + cb11) * cw21;
#pragma unroll
        for (int off = 1; off < 16; off <<= 1) {
#pragma unroll
            for (int r = 0; r < 4; ++r) pp[r] += __shfl_xor(pp[r], off);
        }

        const int tile_base = wave_id * (TPW * 16) + t * 16;
        const float sv = pp[m16 & 3] + cb2;
        if (m16 < 4) {
            ((float4*)pu_buf)[tile_base + ep] = make_float4(sd0 * sv, sd1 * sv, sd2 * sv, 0.0f);
        }

        // ---- rotate pipeline ----
        xi_c = xi_t; xj_c = xj_t;
        pi0_c = ti0; pi1_c = ti1; pi2_c = ti2;
        pj0_c = tj0; pj1_c = tj1; pj2_c = tj2;
        v_n = vA;
    }
}

// ---------------- K6: fused gather + node post (R7-verified) ----------------
__global__ __launch_bounds__(256) void node_post_mfma_kernel(
    const unsigned short* __restrict__ x_bf, const unsigned short* __restrict__ m_buf,
    const float* __restrict__ pu_buf,
    const int* __restrict__ offsets, const int* __restrict__ cnt_int,
    const float* __restrict__ pos, const unsigned short* __restrict__ wf,
    const float* __restrict__ comb_b1, const float* __restrict__ comb_b2,
    float* __restrict__ out_x, float* __restrict__ out_pos) {
    __shared__ float Lh[4][16 * 36];
    __shared__ float Lx[4][16 * 36];
    const int tid = threadIdx.x;
    const int wv = tid >> 6, lane = tid & 63;
    const int m16 = lane & 15, q = lane >> 4;
    const int wave_id = blockIdx.x * 4 + wv;
    if (wave_id * 16 >= NNODE) return;
    const int n = wave_id * 16 + m16;
    float* LH = Lh[wv];
    float* LX = Lx[wv];

    bf16x8 F[6];
#pragma unroll
    for (int f = 0; f < 6; ++f) F[f] = *(const bf16x8*)(wf + (12 + f) * 512 + lane * 8);
    const float b1c0 = comb_b1[m16], b1c1 = comb_b1[16 + m16];
    const float b2c0 = comb_b2[m16], b2c1 = comb_b2[16 + m16];

    const bf16x8 xa = *(const bf16x8*)(x_bf + (size_t)n * HID + q * 8);
    {
        f32x4 xd0, xd1;
#pragma unroll
        for (int jj = 0; jj < 4; ++jj) {
            xd0[jj] = bf16tof((unsigned short)xa[jj]);
            xd1[jj] = bf16tof((unsigned short)xa[4 + jj]);
        }
        *(f32x4*)(LX + m16 * 36 + q * 8) = xd0;
        *(f32x4*)(LX + m16 * 36 + q * 8 + 4) = xd1;
    }

    // gather m_i: 8-way unrolled (deg mean ~8 -> most loads in flight in one round)
    const int off = offsets[n];
    const int deg = cnt_int[n];
    float acc0[8] = {0.f, 0.f, 0.f, 0.f, 0.f, 0.f, 0.f, 0.f};
    float acc1[8] = {0.f, 0.f, 0.f, 0.f, 0.f, 0.f, 0.f, 0.f};
    int d = 0;
    for (; d + 8 <= deg; d += 8) {
        const bf16x8 m0 = *(const bf16x8*)(m_buf + (size_t)(off + d) * HID + q * 8);
        const bf16x8 m1 = *(const bf16x8*)(m_buf + (size_t)(off + d + 1) * HID + q * 8);
        const bf16x8 m2 = *(const bf16x8*)(m_buf + (size_t)(off + d + 2) * HID + q * 8);
        const bf16x8 m3 = *(const bf16x8*)(m_buf + (size_t)(off + d + 3) * HID + q * 8);
        const bf16x8 m4 = *(const bf16x8*)(m_buf + (size_t)(off + d + 4) * HID + q * 8);
        const bf16x8 m5 = *(const bf16x8*)(m_buf + (size_t)(off + d + 5) * HID + q * 8);
        const bf16x8 m6 = *(const bf16x8*)(m_buf + (size_t)(off + d + 6) * HID + q * 8);
        const bf16x8 m7 = *(const bf16x8*)(m_buf + (size_t)(off + d + 7) * HID + q * 8);
#pragma unroll
        for (int jj = 0; jj < 8; ++jj) {
            acc0[jj] += (bf16tof((unsigned short)m0[jj]) + bf16tof((unsigned short)m2[jj]))
                      + (bf16tof((unsigned short)m4[jj]) + bf16tof((unsigned short)m6[jj]));
            acc1[jj] += (bf16tof((unsigned short)m1[jj]) + bf16tof((unsigned short)m3[jj]))
                      + (bf16tof((unsigned short)m5[jj]) + bf16tof((unsigned short)m7[jj]));
        }
    }
    for (; d + 2 <= deg; d += 2) {
        const bf16x8 m0 = *(const bf16x8*)(m_buf + (size_t)(off + d) * HID + q * 8);
        const bf16x8 m1 = *(const bf16x8*)(m_buf + (size_t)(off + d + 1) * HID + q * 8);
#pragma unroll
        for (int jj = 0; jj < 8; ++jj) {
            acc0[jj] += bf16tof((unsigned short)m0[jj]);
            acc1[jj] += bf16tof((unsigned short)m1[jj]);
        }
    }
    if (d < deg) {
        const bf16x8 m0 = *(const bf16x8*)(m_buf + (size_t)(off + d) * HID + q * 8);
#pragma unroll
        for (int jj = 0; jj < 8; ++jj) acc0[jj] += bf16tof((unsigned short)m0[jj]);
    }
    bf16x8 mi;
    { union { unsigned int u[4]; bf16x8 v; } rr;
      rr.u[0] = pk2(acc0[0] + acc1[0], acc0[1] + acc1[1]);
      rr.u[1] = pk2(acc0[2] + acc1[2], acc0[3] + acc1[3]);
      rr.u[2] = pk2(acc0[4] + acc1[4], acc0[5] + acc1[5]);
      rr.u[3] = pk2(acc0[6] + acc1[6], acc0[7] + acc1[7]);
      mi = rr.v; }

    float a0 = 0.f, a1 = 0.f, a2 = 0.f;
    for (int dd = q; dd < deg; dd += 4) {
        const float4 p = ((const float4*)pu_buf)[off + dd];
        a0 += p.x; a1 += p.y; a2 += p.z;
    }
    a0 += __shfl_xor(a0, 16); a0 += __shfl_xor(a0, 32);
    a1 += __shfl_xor(a1, 16); a1 += __shfl_xor(a1, 32);
    a2 += __shfl_xor(a2, 16); a2 += __shfl_xor(a2, 32);

    const f32x4 z = {0.f, 0.f, 0.f, 0.f};
    f32x4 h0 = MFMA16(xa, F[0], z); h0 = MFMA16(mi, F[2], h0);
    f32x4 h1 = MFMA16(xa, F[1], z); h1 = MFMA16(mi, F[3], h1);
#pragma unroll
    for (int r = 0; r < 4; ++r) {
        LH[(q * 4 + r) * 36 + m16]      = silu_f(h0[r] + b1c0);
        LH[(q * 4 + r) * 36 + 16 + m16] = silu_f(h1[r] + b1c1);
    }
    __builtin_amdgcn_s_waitcnt(0xC07F);
    f32x4 ha0 = *(const f32x4*)(LH + m16 * 36 + q * 8);
    f32x4 ha1 = *(const f32x4*)(LH + m16 * 36 + q * 8 + 4);
    const bf16x8 hf = pack8(ha0, ha1);

    f32x4 c0 = MFMA16(hf, F[4], z), c1 = MFMA16(hf, F[5], z);
#pragma unroll
    for (int r = 0; r < 4; ++r) {
        const float xv0 = LX[(q * 4 + r) * 36 + m16];
        const float xv1 = LX[(q * 4 + r) * 36 + 16 + m16];
        LH[(q * 4 + r) * 36 + m16]      = silu_f(xv0 + c0[r] + b2c0);
        LH[(q * 4 + r) * 36 + 16 + m16] = silu_f(xv1 + c1[r] + b2c1);
    }
    __builtin_amdgcn_s_waitcnt(0xC07F);
    {
        const int row = lane >> 2, col = (lane & 3) * 8;
        f32x4 o0 = *(const f32x4*)(LH + row * 36 + col);
        f32x4 o1 = *(const f32x4*)(LH + row * 36 + col + 4);
        float* dst = out_x + (size_t)(wave_id * 16 + row) * HID + col;
        *(f32x4*)dst = o0;
        *(f32x4*)(dst + 4) = o1;
    }
    if (q == 0) {
        const float inv = __builtin_amdgcn_rcpf(fmaxf((float)deg, 1.0f));
        out_pos[n * 3 + 0] = fmaf(a0, inv, pos[n * 3 + 0]);
        out_pos[n * 3 + 1] = fmaf(a1, inv, pos[n * 3 + 1]);
        out_pos[n * 3 + 2] = fmaf(a2, inv, pos[n * 3 + 2]);
    }
}

// ---------------- launch ----------------
extern "C" void kernel_launch(void* const* d_in, const int* in_sizes, int n_in,
                              void* d_out, int out_size, void* d_ws, size_t ws_size,
                              hipStream_t stream) {
    const float* x        = (const float*)d_in[0];
    const int*   ei       = (const int*)d_in[1];
    const float* pos      = (const float*)d_in[2];
    const float* timein   = (const float*)d_in[3];
    const int*   batch    = (const int*)d_in[4];
    const float* rbfm     = (const float*)d_in[5];
    const float* rbfb     = (const float*)d_in[6];
    const float* w_dist   = (const float*)d_in[7];
    const float* msg_w1   = (const float*)d_in[8];
    const float* msg_b1   = (const float*)d_in[9];
    const float* msg_w2   = (const float*)d_in[10];
    const float* msg_b2   = (const float*)d_in[11];
    const float* gate_w   = (const float*)d_in[12];
    const float* gate_b   = (const float*)d_in[13];
    const float* time_w1  = (const float*)d_in[14];
    const float* time_b1  = (const float*)d_in[15];
    const float* time_w2  = (const float*)d_in[16];
    const float* time_b2  = (const float*)d_in[17];
    const float* comb_w1  = (const float*)d_in[18];
    const float* comb_b1  = (const float*)d_in[19];
    const float* comb_w2  = (const float*)d_in[20];
    const float* comb_b2  = (const float*)d_in[21];
    const float* coord_w1 = (const float*)d_in[22];
    const float* coord_b1 = (const float*)d_in[23];
    const float* coord_w2 = (const float*)d_in[24];
    const float* coord_b2 = (const float*)d_in[25];

    char* w = (char*)d_ws;
    float* ss      = (float*)w;  w += (size_t)NGRAPH * 64 * 4;
    int*   cnt     = (int*)w;    w += (size_t)NNODE * 4;
    int*   offsets = (int*)w;    w += (size_t)NNODE * 4;
    int*   part    = (int*)w;    w += (size_t)NBLK1 * SCAN_BLK * 4;
    int*   blk     = (int*)w;    w += 128 * 4;
    int*   rank    = (int*)w;    w += (size_t)NEDGE * 4;
    w = (char*)(((size_t)w + 15) & ~(size_t)15);
    int2*  es      = (int2*)w;   w += (size_t)NEDGE * 8;
    unsigned short* x_bf = (unsigned short*)w;  w += (size_t)NNODE * HID * 2;
    unsigned short* wf   = (unsigned short*)w;  w += (size_t)NFRAG * 512 * 2;
    w = (char*)(((size_t)w + 15) & ~(size_t)15);
    unsigned short* m_buf = (unsigned short*)w; w += (size_t)NEDGE * HID * 2;
    float* pu_buf  = (float*)w;

    float* out_x   = (float*)d_out;
    float* out_pos = out_x + NNODE * HID;

    time_mlp_kernel<<<NGRAPH, 64, 0, stream>>>(timein, time_w1, time_b1, time_w2, time_b2,
                                               ss, cnt);
    fused_pre_kernel<<<NEDGE / 256, 256, 0, stream>>>(x, batch, ss, ei, x_bf, cnt,
                                                      rank,
                                                      msg_w1, msg_w2, gate_w, w_dist,
                                                      coord_w1, comb_w1, comb_w2, wf);
    scan1_kernel<<<NBLK1, SCAN_BLK, 0, stream>>>(cnt, part, blk);
    scatter23_kernel<<<NEDGE / 256, 256, 0, stream>>>(part, blk, ei, rank, offsets, es);
    edge_mfma_kernel<<<NEDGE / (TPW * 64), 256, 0, stream>>>(es, x_bf, pos, rbfm, rbfb, wf,
                                                             msg_b1, msg_b2, gate_b, coord_b1,
                                                             coord_w2, coord_b2,
                                                             m_buf, pu_buf);
    node_post_mfma_kernel<<<(NNODE / 16 + 3) / 4, 256, 0, stream>>>(x_bf, m_buf, pu_buf,
                                                                    offsets, cnt, pos, wf,
                                                                    comb_b1, comb_b2,
                                                                    out_x, out_pos);
}